// Round 4
// baseline (751.537 us; speedup 1.0000x reference)
//
#include <hip/hip_runtime.h>

// GAT layer, N=8192, H=4, d=128.
// softmax_j(src_i + tgt_j) masked == adj-normalized w_j = exp(tgt_j); src cancels:
//   out[i,d] = 0.25 * sum_h ( (adj @ (w_h*ht_h))[i,d] / (adj @ w_h)[i] )
// Pipeline:
//   k0: Wt = W^T
//   k1: HT = leakyrelu(h @ W) bf16 MFMA        [8192 x 512]
//   k2: build Yt bf16 [528][8192]: rows 0..511 = w[g,j]*ht[j,g,d];
//       512..515 = w[g,j]; 516..527 = 0.
//   k3: adj_gemm v4: BM=64 x BN=512 (+den), grid (128,4), 4 waves.
//       PROLOGUE: ballot-pack the block's whole adj slab (64x2048 int32)
//       into a 16KB LDS bitmask; one barrier. K-LOOP: ZERO barriers,
//       zero global A traffic -- A fragments expanded bits->bf16 via a
//       conflict-free 16-entry LDS LUT; B (Yt) direct global->reg (L2-hot).
//   k4: out = 0.25 * sum_g (sum_kh C_kh)[i,512g+d] / (sum_kh S_kh)[g,i]
// ws ~85 MB: Wt 0.5M | HT 8M | Yt 8.65M | C 64M | S 0.5M

typedef unsigned short u16;
typedef unsigned int u32;
typedef unsigned long long u64;
using bf16x8 = __attribute__((ext_vector_type(8))) short;
using f32x4  = __attribute__((ext_vector_type(4))) float;

__device__ __forceinline__ u16 f2bf(float f) {
  u32 u = __float_as_uint(f);
  return (u16)((u + 0x7FFFu + ((u >> 16) & 1u)) >> 16);  // RNE
}
__device__ __forceinline__ float bf2f(u16 u) {
  return __uint_as_float(((u32)u) << 16);
}

// ---------------- k0: transpose W [256][512] -> Wt [512][256] ----------------
__global__ void transpose_w(const float* __restrict__ W, float* __restrict__ Wt) {
  __shared__ float tile[32][33];
  int cb = blockIdx.x * 32, kb = blockIdx.y * 32;
  int tc = threadIdx.x & 31, tr = threadIdx.x >> 5;
  for (int p = 0; p < 32; p += 8)
    tile[tr + p][tc] = W[(size_t)(kb + tr + p) * 512 + cb + tc];
  __syncthreads();
  for (int p = 0; p < 32; p += 8)
    Wt[(size_t)(cb + tr + p) * 256 + kb + tc] = tile[tc][tr + p];
}

// ---------------- k1: HT = leaky(h @ W), bf16 out [8192][512] ----------------
__global__ void ht_gemm(const float* __restrict__ h, const float* __restrict__ Wt,
                        u16* __restrict__ HT) {
  __shared__ __align__(16) u16 Abuf[128 * 40];
  __shared__ __align__(16) u16 Bbuf[128 * 40];
  int tid = threadIdx.x;
  int cb = blockIdx.x, rb = blockIdx.y;
  int r0 = rb * 128, c0 = cb * 128;
  int lane = tid & 63, wv = tid >> 6;
  int wr = wv >> 1, wc = wv & 1;
  int mrow = lane & 15, q = lane >> 4;
  int ch = tid & 7, m0 = tid >> 3;

  f32x4 acc[4][4];
#pragma unroll
  for (int i = 0; i < 4; i++)
#pragma unroll
    for (int j = 0; j < 4; j++) acc[i][j] = f32x4{0.f, 0.f, 0.f, 0.f};

  for (int kt = 0; kt < 256; kt += 32) {
    __syncthreads();
#pragma unroll
    for (int mp = 0; mp < 128; mp += 32) {
      int m = m0 + mp;
      float4 v = *(const float4*)(&h[(size_t)(r0 + m) * 256 + kt + ch * 4]);
      uint2 p;
      p.x = (u32)f2bf(v.x) | ((u32)f2bf(v.y) << 16);
      p.y = (u32)f2bf(v.z) | ((u32)f2bf(v.w) << 16);
      *(uint2*)(&Abuf[m * 40 + ch * 4]) = p;
      float4 u = *(const float4*)(&Wt[(size_t)(c0 + m) * 256 + kt + ch * 4]);
      uint2 r;
      r.x = (u32)f2bf(u.x) | ((u32)f2bf(u.y) << 16);
      r.y = (u32)f2bf(u.z) | ((u32)f2bf(u.w) << 16);
      *(uint2*)(&Bbuf[m * 40 + ch * 4]) = r;
    }
    __syncthreads();
    bf16x8 af[4], bfv[4];
#pragma unroll
    for (int i = 0; i < 4; i++)
      af[i] = *(const bf16x8*)(&Abuf[(wr * 64 + i * 16 + mrow) * 40 + q * 8]);
#pragma unroll
    for (int j = 0; j < 4; j++)
      bfv[j] = *(const bf16x8*)(&Bbuf[(wc * 64 + j * 16 + mrow) * 40 + q * 8]);
#pragma unroll
    for (int i = 0; i < 4; i++)
#pragma unroll
      for (int j = 0; j < 4; j++)
        acc[i][j] = __builtin_amdgcn_mfma_f32_16x16x32_bf16(af[i], bfv[j], acc[i][j], 0, 0, 0);
  }
#pragma unroll
  for (int i = 0; i < 4; i++)
#pragma unroll
    for (int j = 0; j < 4; j++)
#pragma unroll
      for (int r = 0; r < 4; r++) {
        int gi = r0 + wr * 64 + i * 16 + q * 4 + r;
        int gc = c0 + wc * 64 + j * 16 + mrow;
        float v = acc[i][j][r];
        v = v >= 0.f ? v : 0.1f * v;
        HT[(size_t)gi * 512 + gc] = f2bf(v);
      }
}

// ---------------- k2: build Yt [528][8192] bf16 ----------------
__global__ void build_yt(const u16* __restrict__ HT, const float* __restrict__ a,
                         u16* __restrict__ Yt) {
  __shared__ u16 sht[64][528];
  __shared__ float swv[64 * 4];
  __shared__ float sa[512];
  int t = threadIdx.x;
  int j0 = blockIdx.x * 64;
  for (int i = t; i < 512; i += 256) {
    int g = i >> 7, d = i & 127;
    sa[i] = a[g * 256 + 128 + d];
  }
#pragma unroll
  for (int p = 0; p < 16; ++p) {
    int el = t + 256 * p;
    int row = el >> 6, col8 = el & 63;
    *(uint4*)(&sht[row][col8 * 8]) = *(const uint4*)(&HT[(size_t)(j0 + row) * 512 + col8 * 8]);
  }
  __syncthreads();
  {
    int jl = t >> 2, g = t & 3;
    float acc = 0.f;
#pragma unroll
    for (int d8 = 0; d8 < 16; ++d8) {
      bf16x8 v = *(const bf16x8*)(&sht[jl][g * 128 + d8 * 8]);
#pragma unroll
      for (int u = 0; u < 8; ++u)
        acc += bf2f((u16)v[u]) * sa[g * 128 + d8 * 8 + u];
    }
    swv[jl * 4 + g] = __expf(acc);
  }
  __syncthreads();
  int oj = (t & 7) * 8, oc = t >> 3;
  for (int pass = 0; pass < 17; ++pass) {
    int c = pass * 32 + oc;
    if (c >= 528) break;
    u32 pk[4] = {0u, 0u, 0u, 0u};
    if (c < 512) {
      int g = c >> 7;
#pragma unroll
      for (int u = 0; u < 4; ++u) {
        int j = oj + 2 * u;
        float v0 = bf2f(sht[j][c]) * swv[j * 4 + g];
        float v1 = bf2f(sht[j + 1][c]) * swv[(j + 1) * 4 + g];
        pk[u] = (u32)f2bf(v0) | ((u32)f2bf(v1) << 16);
      }
    } else if (c < 516) {
      int g = c - 512;
#pragma unroll
      for (int u = 0; u < 4; ++u) {
        int j = oj + 2 * u;
        float v0 = swv[j * 4 + g];
        float v1 = swv[(j + 1) * 4 + g];
        pk[u] = (u32)f2bf(v0) | ((u32)f2bf(v1) << 16);
      }
    }
    *(uint4*)(&Yt[(size_t)c * 8192 + j0 + oj]) = make_uint4(pk[0], pk[1], pk[2], pk[3]);
  }
}

// ---------------- k3: adj GEMM v4 -- bitmask A, barrier-free K-loop --------
// grid (128, 4) = (rb, kh), 256 threads = 4 waves, wave tile 64x128.
// Prologue: ballot-pack adj slab (64 rows x 2048 k) -> sA[64][65] u32 bits.
// K-loop (64 steps, NO barriers): A-frags = LUT-expand of mask bytes;
// B-frags straight from Yt (global, L2-resident). MFMA accumulate.
__global__ __launch_bounds__(256, 2) void adj_gemm(const int* __restrict__ adj,
                                                   const u16* __restrict__ Yt,
                                                   float* __restrict__ C,
                                                   float* __restrict__ S) {
  __shared__ u32 sA[64][65];       // 16.6 KB bitmask, +1 pad -> conflict-free
  __shared__ u32 sLUT[16][2];      // nibble -> 2 u32 (4 bf16); 128B = 32 banks
  int tid = threadIdx.x;
  int rb = blockIdx.x, kh = blockIdx.y;
  int r0 = rb * 64, k0 = kh * 2048;
  int lane = tid & 63, wv = tid >> 6;
  int mrow = lane & 15, q = lane >> 4;

  // LUT init: nibble n -> {pair(b0,b1), pair(b2,b3)} as bf16 {0,1}
  if (tid < 16) {
    u32 n = tid;
    sLUT[n][0] = ((n & 1u) ? 0x3F80u : 0u) | ((n & 2u) ? 0x3F800000u : 0u);
    sLUT[n][1] = ((n & 4u) ? 0x3F80u : 0u) | ((n & 8u) ? 0x3F800000u : 0u);
  }

  // ---- prologue: ballot-pack adj slab into sA ----
  // 2048 units of 64 bits: unit = (row, u), k = k0 + u*64 + lane
#pragma unroll 8
  for (int it = wv; it < 2048; it += 4) {
    int row = it >> 5, u = it & 31;
    int v = adj[(size_t)(r0 + row) * 8192 + k0 + u * 64 + lane];
    u64 m = __ballot(v != 0);
    if (!(lane & 31)) sA[row][u * 2 + (lane >> 5)] = (u32)(m >> lane);
  }
  __syncthreads();

  // B fragment bases (per lane): row = wv*128 + j*16 + mrow, col = k0 + q*8
  const u16* bbase = &Yt[(size_t)(wv * 128 + mrow) * 8192 + k0 + q * 8];
  const u16* dbase = &Yt[(size_t)(512 + mrow) * 8192 + k0 + q * 8];

  f32x4 acc[4][8];
#pragma unroll
  for (int i = 0; i < 4; i++)
#pragma unroll
    for (int j = 0; j < 8; j++) acc[i][j] = f32x4{0.f, 0.f, 0.f, 0.f};
  f32x4 accD[4];
#pragma unroll
  for (int i = 0; i < 4; i++) accD[i] = f32x4{0.f, 0.f, 0.f, 0.f};

  u32 sh = q * 8;  // byte select within the 32-bit k-dword

  for (int t = 0; t < 64; ++t) {
    // ---- B fragments: global (L2-hot; adj stream already done) ----
    bf16x8 bfv[8];
    size_t koff = (size_t)t * 32;
#pragma unroll
    for (int j = 0; j < 8; j++)
      bfv[j] = *(const bf16x8*)(bbase + (size_t)j * 16 * 8192 + koff);
    bf16x8 bd;
    if (wv == 0) bd = *(const bf16x8*)(dbase + koff);
    // ---- A fragments: mask -> LUT expand (broadcast LDS reads) ----
    bf16x8 af[4];
#pragma unroll
    for (int i = 0; i < 4; i++) {
      u32 m = sA[i * 16 + mrow][t];
      u32 b = (m >> sh) & 0xFFu;
      u32 w[4];
      *(uint2*)&w[0] = *(const uint2*)&sLUT[b & 15u][0];
      *(uint2*)&w[2] = *(const uint2*)&sLUT[b >> 4][0];
      af[i] = *(const bf16x8*)&w[0];
    }
    // ---- MFMAs ----
#pragma unroll
    for (int j = 0; j < 8; j++)
#pragma unroll
      for (int i = 0; i < 4; i++)
        acc[i][j] = __builtin_amdgcn_mfma_f32_16x16x32_bf16(af[i], bfv[j], acc[i][j], 0, 0, 0);
    if (wv == 0) {
#pragma unroll
      for (int i = 0; i < 4; i++)
        accD[i] = __builtin_amdgcn_mfma_f32_16x16x32_bf16(af[i], bd, accD[i], 0, 0, 0);
    }
  }

  float* Ck = C + (size_t)kh * 8192 * 512;
#pragma unroll
  for (int i = 0; i < 4; i++)
#pragma unroll
    for (int j = 0; j < 8; j++)
#pragma unroll
      for (int r = 0; r < 4; r++) {
        int gi = r0 + i * 16 + q * 4 + r;
        int gc = wv * 128 + j * 16 + mrow;
        Ck[(size_t)gi * 512 + gc] = acc[i][j][r];
      }
  if (wv == 0 && mrow < 4) {
    float* Sk = S + (size_t)kh * 4 * 8192;
#pragma unroll
    for (int i = 0; i < 4; i++)
#pragma unroll
      for (int r = 0; r < 4; r++) {
        int gi = r0 + i * 16 + q * 4 + r;
        Sk[(size_t)mrow * 8192 + gi] = accD[i][r];
      }
  }
}

// ---------------- k4: combine K-split + heads ----------------
__global__ void finalize_gat(const float* __restrict__ C, const float* __restrict__ S,
                             float* __restrict__ out) {
  int idx = blockIdx.x * 256 + threadIdx.x;
  int i = idx >> 7, d = idx & 127;
  float s = 0.f;
#pragma unroll
  for (int g = 0; g < 4; ++g) {
    float num = 0.f, den = 0.f;
#pragma unroll
    for (int kh = 0; kh < 4; ++kh) {
      num += C[(size_t)kh * 8192 * 512 + (size_t)i * 512 + g * 128 + d];
      den += S[(size_t)kh * 4 * 8192 + (size_t)g * 8192 + i];
    }
    s += num / den;
  }
  out[idx] = 0.25f * s;
}

extern "C" void kernel_launch(void* const* d_in, const int* in_sizes, int n_in,
                              void* d_out, int out_size, void* d_ws, size_t ws_size,
                              hipStream_t stream) {
  const float* h   = (const float*)d_in[0];
  const int*   adj = (const int*)d_in[1];
  const float* W   = (const float*)d_in[2];
  const float* a   = (const float*)d_in[3];
  float* out = (float*)d_out;
  char* ws = (char*)d_ws;
  // ws: Wt 0.5M | HT 8M | Yt 8.65M | C 64M (4 x 16M) | S 0.5M  (~85 MB)
  float* Wt = (float*)(ws + 0);
  u16*   HT = (u16*)(ws + 524288);
  u16*   Yt = (u16*)(ws + 8912896);
  float* C  = (float*)(ws + 17563648);
  float* S  = (float*)(ws + 84672512);

  transpose_w<<<dim3(16, 8), 256, 0, stream>>>(W, Wt);
  ht_gemm<<<dim3(4, 64), 256, 0, stream>>>(h, Wt, HT);
  build_yt<<<dim3(128), 256, 0, stream>>>(HT, a, Yt);
  adj_gemm<<<dim3(128, 4), 256, 0, stream>>>(adj, Yt, C, S);
  finalize_gat<<<dim3(4096), 256, 0, stream>>>(C, S, out);
}

// Round 5
// 514.116 us; speedup vs baseline: 1.4618x; 1.4618x over previous
//
#include <hip/hip_runtime.h>

// GAT layer, N=8192, H=4, d=128.
// softmax_j(src_i + tgt_j) masked == adj-normalized w_j = exp(tgt_j); src cancels:
//   out[i,d] = 0.25 * sum_h ( (adj @ (w_h*ht_h))[i,d] / (adj @ w_h)[i] )
// Pipeline:
//   k0: Wt = W^T
//   k1: HT = leakyrelu(h @ W) bf16 MFMA        [8192 x 512]
//   k2: build_yt bf16 [528][8192] (grid 256, 32-j slabs)
//   k3: adj_gemm (r0-proven structure, BM=128, 8 waves, GLD16 B-staging)
//       + kh->XCD pinning: grid (4,64) => linear id = kh + 4*rb, id%8 in
//         {kh, kh+4}: each XCD serves ONE kh quarter (2.16 MB, L2-resident).
//       + non-temporal adj loads / C,S stores (don't evict Yt from L2).
//   k4: out = 0.25 * sum_g (sum_kh C_kh)[i,512g+d] / (sum_kh S_kh)[g,i]
// ws ~85 MB: Wt 0.5M | HT 8M | Yt 8.65M | C 64M | S 0.5M

typedef unsigned short u16;
typedef unsigned int u32;
using bf16x8 = __attribute__((ext_vector_type(8))) short;
using f32x4  = __attribute__((ext_vector_type(4))) float;
using i32x4  = __attribute__((ext_vector_type(4))) int;

typedef const void __attribute__((address_space(1))) gas_void;
typedef void __attribute__((address_space(3))) las_void;
#define GLD16(g, l) __builtin_amdgcn_global_load_lds((gas_void*)(g), (las_void*)(l), 16, 0, 0)

__device__ __forceinline__ u16 f2bf(float f) {
  u32 u = __float_as_uint(f);
  return (u16)((u + 0x7FFFu + ((u >> 16) & 1u)) >> 16);  // RNE
}
__device__ __forceinline__ float bf2f(u16 u) {
  return __uint_as_float(((u32)u) << 16);
}

// ---------------- k0: transpose W [256][512] -> Wt [512][256] ----------------
__global__ void transpose_w(const float* __restrict__ W, float* __restrict__ Wt) {
  __shared__ float tile[32][33];
  int cb = blockIdx.x * 32, kb = blockIdx.y * 32;
  int tc = threadIdx.x & 31, tr = threadIdx.x >> 5;
  for (int p = 0; p < 32; p += 8)
    tile[tr + p][tc] = W[(size_t)(kb + tr + p) * 512 + cb + tc];
  __syncthreads();
  for (int p = 0; p < 32; p += 8)
    Wt[(size_t)(cb + tr + p) * 256 + kb + tc] = tile[tc][tr + p];
}

// ---------------- k1: HT = leaky(h @ W), bf16 out [8192][512] ----------------
__global__ void ht_gemm(const float* __restrict__ h, const float* __restrict__ Wt,
                        u16* __restrict__ HT) {
  __shared__ __align__(16) u16 Abuf[128 * 40];
  __shared__ __align__(16) u16 Bbuf[128 * 40];
  int tid = threadIdx.x;
  int cb = blockIdx.x, rb = blockIdx.y;
  int r0 = rb * 128, c0 = cb * 128;
  int lane = tid & 63, wv = tid >> 6;
  int wr = wv >> 1, wc = wv & 1;
  int mrow = lane & 15, q = lane >> 4;
  int ch = tid & 7, m0 = tid >> 3;

  f32x4 acc[4][4];
#pragma unroll
  for (int i = 0; i < 4; i++)
#pragma unroll
    for (int j = 0; j < 4; j++) acc[i][j] = f32x4{0.f, 0.f, 0.f, 0.f};

  for (int kt = 0; kt < 256; kt += 32) {
    __syncthreads();
#pragma unroll
    for (int mp = 0; mp < 128; mp += 32) {
      int m = m0 + mp;
      float4 v = *(const float4*)(&h[(size_t)(r0 + m) * 256 + kt + ch * 4]);
      uint2 p;
      p.x = (u32)f2bf(v.x) | ((u32)f2bf(v.y) << 16);
      p.y = (u32)f2bf(v.z) | ((u32)f2bf(v.w) << 16);
      *(uint2*)(&Abuf[m * 40 + ch * 4]) = p;
      float4 u = *(const float4*)(&Wt[(size_t)(c0 + m) * 256 + kt + ch * 4]);
      uint2 r;
      r.x = (u32)f2bf(u.x) | ((u32)f2bf(u.y) << 16);
      r.y = (u32)f2bf(u.z) | ((u32)f2bf(u.w) << 16);
      *(uint2*)(&Bbuf[m * 40 + ch * 4]) = r;
    }
    __syncthreads();
    bf16x8 af[4], bfv[4];
#pragma unroll
    for (int i = 0; i < 4; i++)
      af[i] = *(const bf16x8*)(&Abuf[(wr * 64 + i * 16 + mrow) * 40 + q * 8]);
#pragma unroll
    for (int j = 0; j < 4; j++)
      bfv[j] = *(const bf16x8*)(&Bbuf[(wc * 64 + j * 16 + mrow) * 40 + q * 8]);
#pragma unroll
    for (int i = 0; i < 4; i++)
#pragma unroll
      for (int j = 0; j < 4; j++)
        acc[i][j] = __builtin_amdgcn_mfma_f32_16x16x32_bf16(af[i], bfv[j], acc[i][j], 0, 0, 0);
  }
#pragma unroll
  for (int i = 0; i < 4; i++)
#pragma unroll
    for (int j = 0; j < 4; j++)
#pragma unroll
      for (int r = 0; r < 4; r++) {
        int gi = r0 + wr * 64 + i * 16 + q * 4 + r;
        int gc = c0 + wc * 64 + j * 16 + mrow;
        float v = acc[i][j][r];
        v = v >= 0.f ? v : 0.1f * v;
        HT[(size_t)gi * 512 + gc] = f2bf(v);
      }
}

// ---------------- k2: build Yt [528][8192] bf16 (32-j slabs, grid 256) -------
__global__ void build_yt(const u16* __restrict__ HT, const float* __restrict__ a,
                         u16* __restrict__ Yt) {
  __shared__ u16 sht[32][528];
  __shared__ float swv[32 * 4];
  __shared__ float sa[512];
  int t = threadIdx.x;
  int j0 = blockIdx.x * 32;
  for (int i = t; i < 512; i += 256) {
    int g = i >> 7, d = i & 127;
    sa[i] = a[g * 256 + 128 + d];
  }
#pragma unroll
  for (int p = 0; p < 8; ++p) {
    int el = t + 256 * p;                 // 2048 uint4 slots: 32 rows x 64
    int row = el >> 6, col8 = el & 63;
    *(uint4*)(&sht[row][col8 * 8]) = *(const uint4*)(&HT[(size_t)(j0 + row) * 512 + col8 * 8]);
  }
  __syncthreads();
  if (t < 128) {
    int jl = t >> 2, g = t & 3;
    float acc = 0.f;
#pragma unroll
    for (int d8 = 0; d8 < 16; ++d8) {
      bf16x8 v = *(const bf16x8*)(&sht[jl][g * 128 + d8 * 8]);
#pragma unroll
      for (int u = 0; u < 8; ++u)
        acc += bf2f((u16)v[u]) * sa[g * 128 + d8 * 8 + u];
    }
    swv[jl * 4 + g] = __expf(acc);
  }
  __syncthreads();
  int oj = (t & 3) * 8, oc = t >> 2;      // 4 j-octets x 64 cols per pass
  for (int pass = 0; pass < 9; ++pass) {
    int c = pass * 64 + oc;
    if (c >= 528) break;
    u32 pk[4] = {0u, 0u, 0u, 0u};
    if (c < 512) {
      int g = c >> 7;
#pragma unroll
      for (int u = 0; u < 4; ++u) {
        int j = oj + 2 * u;
        float v0 = bf2f(sht[j][c]) * swv[j * 4 + g];
        float v1 = bf2f(sht[j + 1][c]) * swv[(j + 1) * 4 + g];
        pk[u] = (u32)f2bf(v0) | ((u32)f2bf(v1) << 16);
      }
    } else if (c < 516) {
      int g = c - 512;
#pragma unroll
      for (int u = 0; u < 4; ++u) {
        int j = oj + 2 * u;
        float v0 = swv[j * 4 + g];
        float v1 = swv[(j + 1) * 4 + g];
        pk[u] = (u32)f2bf(v0) | ((u32)f2bf(v1) << 16);
      }
    }
    *(uint4*)(&Yt[(size_t)c * 8192 + j0 + oj]) = make_uint4(pk[0], pk[1], pk[2], pk[3]);
  }
}

// ---------------- k3: fused adj GEMM (r0 structure + kh->XCD pinning) --------
// grid (4, 64) = (kh, rb): linear id = kh + 4*rb -> XCD = id%8 in {kh, kh+4};
// each XCD serves ONE Yt quarter (2.16 MB < 4 MB L2), shared by its 32 blocks.
// 512 threads = 8 waves (2 wr x 4 wc), wave tile 64x128, BM=128, BK=32.
// adj loads + C/S stores non-temporal: streaming traffic must not evict Yt.
__global__ __launch_bounds__(512) void adj_gemm(const int* __restrict__ adj,
                                                const u16* __restrict__ Yt,
                                                float* __restrict__ C,
                                                float* __restrict__ S) {
  __shared__ __align__(16) u16 Abuf[128 * 32];   // 8 KB
  __shared__ __align__(16) u16 Bbuf[512 * 32];   // 32 KB
  __shared__ __align__(16) u16 Bden[16 * 32];    // 1 KB
  int tid = threadIdx.x;
  int rb = blockIdx.y, kh = blockIdx.x;          // <- pinning: kh fastest
  int r0 = rb * 128, k0 = kh * 2048;
  int lane = tid & 63, wv = tid >> 6;
  int wr = wv >> 2, wc = wv & 3;
  int mrow = lane & 15, q = lane >> 4;
  int am = tid >> 2, ak = (tid & 3) * 8;   // A staging: row, k-octet
  int brow = lane >> 2, bq = lane & 3;     // B staging lane split
  bool do_den = (wc == 0);

  f32x4 acc[4][8];
#pragma unroll
  for (int i = 0; i < 4; i++)
#pragma unroll
    for (int j = 0; j < 8; j++) acc[i][j] = f32x4{0.f, 0.f, 0.f, 0.f};
  f32x4 accD[4];
#pragma unroll
  for (int i = 0; i < 4; i++) accD[i] = f32x4{0.f, 0.f, 0.f, 0.f};

  for (int kt = k0; kt < k0 + 2048; kt += 32) {
    __syncthreads();
    {  // A: 128 rows x 32 k, int32 -> bf16, non-temporal (read-once stream)
      const int* ap = &adj[(size_t)(r0 + am) * 8192 + kt + ak];
      i32x4 v0 = __builtin_nontemporal_load((const i32x4*)(ap));
      i32x4 v1 = __builtin_nontemporal_load((const i32x4*)(ap + 4));
      uint4 p;  // {0,1} -> bf16 bits 0x3F80*x, packed pairwise
      p.x = 16256u * ((u32)v0[0] | ((u32)v0[1] << 16));
      p.y = 16256u * ((u32)v0[2] | ((u32)v0[3] << 16));
      p.z = 16256u * ((u32)v1[0] | ((u32)v1[1] << 16));
      p.w = 16256u * ((u32)v1[2] | ((u32)v1[3] << 16));
      *(uint4*)(&Abuf[am * 32 + ak]) = p;
    }
    // B: 512 rows x 32 k via async global->LDS (16 rows per wave-call)
#pragma unroll
    for (int p = 0; p < 4; ++p)
      GLD16(&Yt[(size_t)(p * 128 + wv * 16 + brow) * 8192 + kt + bq * 8],
            &Bbuf[(p * 128 + wv * 16) * 32]);
    if (wv == 0)
      GLD16(&Yt[(size_t)(512 + brow) * 8192 + kt + bq * 8], Bden);
    __syncthreads();
    bf16x8 af[4], bfv[8];
#pragma unroll
    for (int i = 0; i < 4; i++)
      af[i] = *(const bf16x8*)(&Abuf[(wr * 64 + i * 16 + mrow) * 32 + q * 8]);
#pragma unroll
    for (int j = 0; j < 8; j++)
      bfv[j] = *(const bf16x8*)(&Bbuf[(wc * 128 + j * 16 + mrow) * 32 + q * 8]);
#pragma unroll
    for (int i = 0; i < 4; i++)
#pragma unroll
      for (int j = 0; j < 8; j++)
        acc[i][j] = __builtin_amdgcn_mfma_f32_16x16x32_bf16(af[i], bfv[j], acc[i][j], 0, 0, 0);
    if (do_den) {
      bf16x8 bd = *(const bf16x8*)(&Bden[mrow * 32 + q * 8]);
#pragma unroll
      for (int i = 0; i < 4; i++)
        accD[i] = __builtin_amdgcn_mfma_f32_16x16x32_bf16(af[i], bd, accD[i], 0, 0, 0);
    }
  }
  float* Ck = C + (size_t)kh * 8192 * 512;
#pragma unroll
  for (int i = 0; i < 4; i++)
#pragma unroll
    for (int j = 0; j < 8; j++)
#pragma unroll
      for (int r = 0; r < 4; r++) {
        int gi = r0 + wr * 64 + i * 16 + q * 4 + r;
        int gc = wc * 128 + j * 16 + mrow;
        __builtin_nontemporal_store(acc[i][j][r], &Ck[(size_t)gi * 512 + gc]);
      }
  if (do_den && mrow < 4) {
    float* Sk = S + (size_t)kh * 4 * 8192;
#pragma unroll
    for (int i = 0; i < 4; i++)
#pragma unroll
      for (int r = 0; r < 4; r++) {
        int gi = r0 + wr * 64 + i * 16 + q * 4 + r;
        __builtin_nontemporal_store(accD[i][r], &Sk[(size_t)mrow * 8192 + gi]);
      }
  }
}

// ---------------- k4: combine K-split + heads ----------------
__global__ void finalize_gat(const float* __restrict__ C, const float* __restrict__ S,
                             float* __restrict__ out) {
  int idx = blockIdx.x * 256 + threadIdx.x;
  int i = idx >> 7, d = idx & 127;
  float s = 0.f;
#pragma unroll
  for (int g = 0; g < 4; ++g) {
    float num = 0.f, den = 0.f;
#pragma unroll
    for (int kh = 0; kh < 4; ++kh) {
      num += C[(size_t)kh * 8192 * 512 + (size_t)i * 512 + g * 128 + d];
      den += S[(size_t)kh * 4 * 8192 + (size_t)g * 8192 + i];
    }
    s += num / den;
  }
  out[idx] = 0.25f * s;
}

extern "C" void kernel_launch(void* const* d_in, const int* in_sizes, int n_in,
                              void* d_out, int out_size, void* d_ws, size_t ws_size,
                              hipStream_t stream) {
  const float* h   = (const float*)d_in[0];
  const int*   adj = (const int*)d_in[1];
  const float* W   = (const float*)d_in[2];
  const float* a   = (const float*)d_in[3];
  float* out = (float*)d_out;
  char* ws = (char*)d_ws;
  // ws: Wt 0.5M | HT 8M | Yt 8.65M | C 64M (4 x 16M) | S 0.5M  (~85 MB)
  float* Wt = (float*)(ws + 0);
  u16*   HT = (u16*)(ws + 524288);
  u16*   Yt = (u16*)(ws + 8912896);
  float* C  = (float*)(ws + 17563648);
  float* S  = (float*)(ws + 84672512);

  transpose_w<<<dim3(16, 8), 256, 0, stream>>>(W, Wt);
  ht_gemm<<<dim3(4, 64), 256, 0, stream>>>(h, Wt, HT);
  build_yt<<<dim3(256), 256, 0, stream>>>(HT, a, Yt);
  adj_gemm<<<dim3(4, 64), 512, 0, stream>>>(adj, Yt, C, S);
  finalize_gat<<<dim3(4096), 256, 0, stream>>>(C, S, out);
}

// Round 6
// 481.269 us; speedup vs baseline: 1.5616x; 1.0683x over previous
//
#include <hip/hip_runtime.h>

// GAT layer, N=8192, H=4, d=128.
// softmax_j(src_i + tgt_j) masked == adj-normalized w_j = exp(tgt_j); src cancels:
//   out[i,d] = 0.25 * sum_h ( (adj @ (w_h*ht_h))[i,d] / (adj @ w_h)[i] )
// Pipeline:
//   k0: Wt = W^T
//   k1: HT = leakyrelu(h @ W) bf16 MFMA        [8192 x 512]
//   k2: build_yt bf16 [528][8192] (grid 256, 32-j slabs)
//   k3: adj_gemm v6: BM=128, BN=512, 8 waves, grid (4,64) kh->XCD pinned
//       (each XCD's L2 holds ONE 2.16MB Yt quarter). Double-buffered
//       GLD16 B-staging overlapped with MFMAs (r1-proven +2x fill rate),
//       one vmcnt+lgkm drain per step AFTER compute covered the latency.
//       nt adj loads (read-once stream must not evict Yt). Normal C/S
//       stores (nt stores cost finalize +28us in r5).
//   k4: out = 0.25 * sum_g (sum_kh C_kh)[i,512g+d] / (sum_kh S_kh)[g,i]
// ws ~85 MB: Wt 0.5M | HT 8M | Yt 8.65M | C 64M | S 0.5M

typedef unsigned short u16;
typedef unsigned int u32;
using bf16x8 = __attribute__((ext_vector_type(8))) short;
using f32x4  = __attribute__((ext_vector_type(4))) float;
using i32x4  = __attribute__((ext_vector_type(4))) int;

typedef const void __attribute__((address_space(1))) gas_void;
typedef void __attribute__((address_space(3))) las_void;
#define GLD16(g, l) __builtin_amdgcn_global_load_lds((gas_void*)(g), (las_void*)(l), 16, 0, 0)

__device__ __forceinline__ u16 f2bf(float f) {
  u32 u = __float_as_uint(f);
  return (u16)((u + 0x7FFFu + ((u >> 16) & 1u)) >> 16);  // RNE
}
__device__ __forceinline__ float bf2f(u16 u) {
  return __uint_as_float(((u32)u) << 16);
}

// ---------------- k0: transpose W [256][512] -> Wt [512][256] ----------------
__global__ void transpose_w(const float* __restrict__ W, float* __restrict__ Wt) {
  __shared__ float tile[32][33];
  int cb = blockIdx.x * 32, kb = blockIdx.y * 32;
  int tc = threadIdx.x & 31, tr = threadIdx.x >> 5;
  for (int p = 0; p < 32; p += 8)
    tile[tr + p][tc] = W[(size_t)(kb + tr + p) * 512 + cb + tc];
  __syncthreads();
  for (int p = 0; p < 32; p += 8)
    Wt[(size_t)(cb + tr + p) * 256 + kb + tc] = tile[tc][tr + p];
}

// ---------------- k1: HT = leaky(h @ W), bf16 out [8192][512] ----------------
__global__ void ht_gemm(const float* __restrict__ h, const float* __restrict__ Wt,
                        u16* __restrict__ HT) {
  __shared__ __align__(16) u16 Abuf[128 * 40];
  __shared__ __align__(16) u16 Bbuf[128 * 40];
  int tid = threadIdx.x;
  int cb = blockIdx.x, rb = blockIdx.y;
  int r0 = rb * 128, c0 = cb * 128;
  int lane = tid & 63, wv = tid >> 6;
  int wr = wv >> 1, wc = wv & 1;
  int mrow = lane & 15, q = lane >> 4;
  int ch = tid & 7, m0 = tid >> 3;

  f32x4 acc[4][4];
#pragma unroll
  for (int i = 0; i < 4; i++)
#pragma unroll
    for (int j = 0; j < 4; j++) acc[i][j] = f32x4{0.f, 0.f, 0.f, 0.f};

  for (int kt = 0; kt < 256; kt += 32) {
    __syncthreads();
#pragma unroll
    for (int mp = 0; mp < 128; mp += 32) {
      int m = m0 + mp;
      float4 v = *(const float4*)(&h[(size_t)(r0 + m) * 256 + kt + ch * 4]);
      uint2 p;
      p.x = (u32)f2bf(v.x) | ((u32)f2bf(v.y) << 16);
      p.y = (u32)f2bf(v.z) | ((u32)f2bf(v.w) << 16);
      *(uint2*)(&Abuf[m * 40 + ch * 4]) = p;
      float4 u = *(const float4*)(&Wt[(size_t)(c0 + m) * 256 + kt + ch * 4]);
      uint2 r;
      r.x = (u32)f2bf(u.x) | ((u32)f2bf(u.y) << 16);
      r.y = (u32)f2bf(u.z) | ((u32)f2bf(u.w) << 16);
      *(uint2*)(&Bbuf[m * 40 + ch * 4]) = r;
    }
    __syncthreads();
    bf16x8 af[4], bfv[4];
#pragma unroll
    for (int i = 0; i < 4; i++)
      af[i] = *(const bf16x8*)(&Abuf[(wr * 64 + i * 16 + mrow) * 40 + q * 8]);
#pragma unroll
    for (int j = 0; j < 4; j++)
      bfv[j] = *(const bf16x8*)(&Bbuf[(wc * 64 + j * 16 + mrow) * 40 + q * 8]);
#pragma unroll
    for (int i = 0; i < 4; i++)
#pragma unroll
      for (int j = 0; j < 4; j++)
        acc[i][j] = __builtin_amdgcn_mfma_f32_16x16x32_bf16(af[i], bfv[j], acc[i][j], 0, 0, 0);
  }
#pragma unroll
  for (int i = 0; i < 4; i++)
#pragma unroll
    for (int j = 0; j < 4; j++)
#pragma unroll
      for (int r = 0; r < 4; r++) {
        int gi = r0 + wr * 64 + i * 16 + q * 4 + r;
        int gc = c0 + wc * 64 + j * 16 + mrow;
        float v = acc[i][j][r];
        v = v >= 0.f ? v : 0.1f * v;
        HT[(size_t)gi * 512 + gc] = f2bf(v);
      }
}

// ---------------- k2: build Yt [528][8192] bf16 (32-j slabs, grid 256) -------
__global__ void build_yt(const u16* __restrict__ HT, const float* __restrict__ a,
                         u16* __restrict__ Yt) {
  __shared__ u16 sht[32][528];
  __shared__ float swv[32 * 4];
  __shared__ float sa[512];
  int t = threadIdx.x;
  int j0 = blockIdx.x * 32;
  for (int i = t; i < 512; i += 256) {
    int g = i >> 7, d = i & 127;
    sa[i] = a[g * 256 + 128 + d];
  }
#pragma unroll
  for (int p = 0; p < 8; ++p) {
    int el = t + 256 * p;                 // 2048 uint4 slots: 32 rows x 64
    int row = el >> 6, col8 = el & 63;
    *(uint4*)(&sht[row][col8 * 8]) = *(const uint4*)(&HT[(size_t)(j0 + row) * 512 + col8 * 8]);
  }
  __syncthreads();
  if (t < 128) {
    int jl = t >> 2, g = t & 3;
    float acc = 0.f;
#pragma unroll
    for (int d8 = 0; d8 < 16; ++d8) {
      bf16x8 v = *(const bf16x8*)(&sht[jl][g * 128 + d8 * 8]);
#pragma unroll
      for (int u = 0; u < 8; ++u)
        acc += bf2f((u16)v[u]) * sa[g * 128 + d8 * 8 + u];
    }
    swv[jl * 4 + g] = __expf(acc);
  }
  __syncthreads();
  int oj = (t & 3) * 8, oc = t >> 2;      // 4 j-octets x 64 cols per pass
  for (int pass = 0; pass < 9; ++pass) {
    int c = pass * 64 + oc;
    if (c >= 528) break;
    u32 pk[4] = {0u, 0u, 0u, 0u};
    if (c < 512) {
      int g = c >> 7;
#pragma unroll
      for (int u = 0; u < 4; ++u) {
        int j = oj + 2 * u;
        float v0 = bf2f(sht[j][c]) * swv[j * 4 + g];
        float v1 = bf2f(sht[j + 1][c]) * swv[(j + 1) * 4 + g];
        pk[u] = (u32)f2bf(v0) | ((u32)f2bf(v1) << 16);
      }
    } else if (c < 516) {
      int g = c - 512;
#pragma unroll
      for (int u = 0; u < 4; ++u) {
        int j = oj + 2 * u;
        float v0 = swv[j * 4 + g];
        float v1 = swv[(j + 1) * 4 + g];
        pk[u] = (u32)f2bf(v0) | ((u32)f2bf(v1) << 16);
      }
    }
    *(uint4*)(&Yt[(size_t)c * 8192 + j0 + oj]) = make_uint4(pk[0], pk[1], pk[2], pk[3]);
  }
}

// ---------------- k3: adj GEMM v6 -- kh-pinned + overlapped dbuf GLD16 ------
// grid (4, 64) = (kh, rb): linear id = kh + 4*rb -> XCD = id%8 in {kh, kh+4};
// each XCD serves ONE Yt quarter (2.16 MB < 4 MB L2).
// 512 threads = 8 waves (2 wr x 4 wc), wave tile 64x128, BM=128, BK=32.
// Per step: issue t+1 GLD16s + nt A-loads FIRST, MFMA tile t (setprio),
// pack/ds_write A(t+1), vmcnt(0)+lgkmcnt(0) (cheap: compute covered the
// latency), ONE raw s_barrier. Double-buffered LDS (82 KB).
__global__ __launch_bounds__(512) void adj_gemm(const int* __restrict__ adj,
                                                const u16* __restrict__ Yt,
                                                float* __restrict__ C,
                                                float* __restrict__ S) {
  __shared__ __align__(16) u16 Abuf[2][128 * 32];   // 2 x 8 KB
  __shared__ __align__(16) u16 Bbuf[2][512 * 32];   // 2 x 32 KB
  __shared__ __align__(16) u16 Bden[2][16 * 32];    // 2 x 1 KB
  int tid = threadIdx.x;
  int rb = blockIdx.y, kh = blockIdx.x;             // kh fastest -> XCD pin
  int r0 = rb * 128, k0 = kh * 2048;
  int lane = tid & 63, wv = tid >> 6;
  int wr = wv >> 2, wc = wv & 3;
  int mrow = lane & 15, q = lane >> 4;
  int am = tid >> 2, ak = (tid & 3) * 8;   // A staging: row, k-octet
  int brow = lane >> 2, bq = lane & 3;     // B staging lane split
  bool do_den = (wc == 0);
  const int* abase = &adj[(size_t)(r0 + am) * 8192 + k0 + ak];

  f32x4 acc[4][8];
#pragma unroll
  for (int i = 0; i < 4; i++)
#pragma unroll
    for (int j = 0; j < 8; j++) acc[i][j] = f32x4{0.f, 0.f, 0.f, 0.f};
  f32x4 accD[4];
#pragma unroll
  for (int i = 0; i < 4; i++) accD[i] = f32x4{0.f, 0.f, 0.f, 0.f};

  // ---- prologue: stage tile 0 into buffer 0 ----
  {
#pragma unroll
    for (int p = 0; p < 4; ++p)
      GLD16(&Yt[(size_t)(p * 128 + wv * 16 + brow) * 8192 + k0 + bq * 8],
            &Bbuf[0][(p * 128 + wv * 16) * 32]);
    if (wv == 0)
      GLD16(&Yt[(size_t)(512 + brow) * 8192 + k0 + bq * 8], &Bden[0][0]);
    i32x4 v0 = __builtin_nontemporal_load((const i32x4*)(abase));
    i32x4 v1 = __builtin_nontemporal_load((const i32x4*)(abase + 4));
    uint4 p;  // {0,1} -> bf16 bits 0x3F80*x, packed pairwise
    p.x = 16256u * ((u32)v0[0] | ((u32)v0[1] << 16));
    p.y = 16256u * ((u32)v0[2] | ((u32)v0[3] << 16));
    p.z = 16256u * ((u32)v1[0] | ((u32)v1[1] << 16));
    p.w = 16256u * ((u32)v1[2] | ((u32)v1[3] << 16));
    *(uint4*)(&Abuf[0][am * 32 + ak]) = p;
  }
  __syncthreads();

  int cur = 0;
  for (int t = 0; t < 64; ++t) {
    int nxt = cur ^ 1;
    int kt = k0 + (t + 1) * 32;
    // ---- issue prefetch of tile t+1 (lands under this tile's MFMAs) ----
    i32x4 v0, v1;
    if (t < 63) {
#pragma unroll
      for (int p = 0; p < 4; ++p)
        GLD16(&Yt[(size_t)(p * 128 + wv * 16 + brow) * 8192 + kt + bq * 8],
              &Bbuf[nxt][(p * 128 + wv * 16) * 32]);
      if (wv == 0)
        GLD16(&Yt[(size_t)(512 + brow) * 8192 + kt + bq * 8], &Bden[nxt][0]);
      const int* ap = abase + (size_t)(t + 1) * 32;
      v0 = __builtin_nontemporal_load((const i32x4*)(ap));
      v1 = __builtin_nontemporal_load((const i32x4*)(ap + 4));
    }
    // ---- compute tile t from buffer cur ----
    bf16x8 af[4], bfv[8];
#pragma unroll
    for (int i = 0; i < 4; i++)
      af[i] = *(const bf16x8*)(&Abuf[cur][(wr * 64 + i * 16 + mrow) * 32 + q * 8]);
#pragma unroll
    for (int j = 0; j < 8; j++)
      bfv[j] = *(const bf16x8*)(&Bbuf[cur][(wc * 128 + j * 16 + mrow) * 32 + q * 8]);
    __builtin_amdgcn_s_setprio(1);
#pragma unroll
    for (int i = 0; i < 4; i++)
#pragma unroll
      for (int j = 0; j < 8; j++)
        acc[i][j] = __builtin_amdgcn_mfma_f32_16x16x32_bf16(af[i], bfv[j], acc[i][j], 0, 0, 0);
    if (do_den) {
      bf16x8 bd = *(const bf16x8*)(&Bden[cur][mrow * 32 + q * 8]);
#pragma unroll
      for (int i = 0; i < 4; i++)
        accD[i] = __builtin_amdgcn_mfma_f32_16x16x32_bf16(af[i], bd, accD[i], 0, 0, 0);
    }
    __builtin_amdgcn_s_setprio(0);
    // ---- finish staging A(t+1) ----
    if (t < 63) {
      uint4 p;
      p.x = 16256u * ((u32)v0[0] | ((u32)v0[1] << 16));
      p.y = 16256u * ((u32)v0[2] | ((u32)v0[3] << 16));
      p.z = 16256u * ((u32)v1[0] | ((u32)v1[1] << 16));
      p.w = 16256u * ((u32)v1[2] | ((u32)v1[3] << 16));
      *(uint4*)(&Abuf[nxt][am * 32 + ak]) = p;
    }
    asm volatile("s_waitcnt vmcnt(0) lgkmcnt(0)" ::: "memory");
    __builtin_amdgcn_s_barrier();
    cur = nxt;
  }

  float* Ck = C + (size_t)kh * 8192 * 512;
#pragma unroll
  for (int i = 0; i < 4; i++)
#pragma unroll
    for (int j = 0; j < 8; j++)
#pragma unroll
      for (int r = 0; r < 4; r++) {
        int gi = r0 + wr * 64 + i * 16 + q * 4 + r;
        int gc = wc * 128 + j * 16 + mrow;
        Ck[(size_t)gi * 512 + gc] = acc[i][j][r];
      }
  if (do_den && mrow < 4) {
    float* Sk = S + (size_t)kh * 4 * 8192;
#pragma unroll
    for (int i = 0; i < 4; i++)
#pragma unroll
      for (int r = 0; r < 4; r++) {
        int gi = r0 + wr * 64 + i * 16 + q * 4 + r;
        Sk[(size_t)mrow * 8192 + gi] = accD[i][r];
      }
  }
}

// ---------------- k4: combine K-split + heads ----------------
__global__ void finalize_gat(const float* __restrict__ C, const float* __restrict__ S,
                             float* __restrict__ out) {
  int idx = blockIdx.x * 256 + threadIdx.x;
  int i = idx >> 7, d = idx & 127;
  float s = 0.f;
#pragma unroll
  for (int g = 0; g < 4; ++g) {
    float num = 0.f, den = 0.f;
#pragma unroll
    for (int kh = 0; kh < 4; ++kh) {
      num += C[(size_t)kh * 8192 * 512 + (size_t)i * 512 + g * 128 + d];
      den += S[(size_t)kh * 4 * 8192 + (size_t)g * 8192 + i];
    }
    s += num / den;
  }
  out[idx] = 0.25f * s;
}

extern "C" void kernel_launch(void* const* d_in, const int* in_sizes, int n_in,
                              void* d_out, int out_size, void* d_ws, size_t ws_size,
                              hipStream_t stream) {
  const float* h   = (const float*)d_in[0];
  const int*   adj = (const int*)d_in[1];
  const float* W   = (const float*)d_in[2];
  const float* a   = (const float*)d_in[3];
  float* out = (float*)d_out;
  char* ws = (char*)d_ws;
  // ws: Wt 0.5M | HT 8M | Yt 8.65M | C 64M (4 x 16M) | S 0.5M  (~85 MB)
  float* Wt = (float*)(ws + 0);
  u16*   HT = (u16*)(ws + 524288);
  u16*   Yt = (u16*)(ws + 8912896);
  float* C  = (float*)(ws + 17563648);
  float* S  = (float*)(ws + 84672512);

  transpose_w<<<dim3(16, 8), 256, 0, stream>>>(W, Wt);
  ht_gemm<<<dim3(4, 64), 256, 0, stream>>>(h, Wt, HT);
  build_yt<<<dim3(256), 256, 0, stream>>>(HT, a, Yt);
  adj_gemm<<<dim3(4, 64), 512, 0, stream>>>(adj, Yt, C, S);
  finalize_gat<<<dim3(4096), 256, 0, stream>>>(C, S, out);
}

// Round 7
// 456.026 us; speedup vs baseline: 1.6480x; 1.0554x over previous
//
#include <hip/hip_runtime.h>

// GAT layer, N=8192, H=4, d=128.
// softmax_j(src_i + tgt_j) masked == adj-normalized w_j = exp(tgt_j); src cancels:
//   out[i,d] = 0.25 * sum_h ( (adj @ (w_h*ht_h))[i,d] / (adj @ w_h)[i] )
// Pipeline:
//   k0: Wt = W^T
//   k1: HT = leakyrelu(h @ W) bf16 MFMA        [8192 x 512]
//   k2: build_yt bf16 [528][8192] (grid 256, 32-j slabs)
//   k3: adj_gemm v7: BM=128, BN=512, 8 waves, grid (4,64) kh->XCD pinned.
//       2-AHEAD GLD16 staging, triple-buffered B LDS, counted vmcnt(4|5)
//       per step (tile t+2 stays in flight across the barrier -- T3/T4).
//       r1-proven XOR swizzle on A and B (source-octet permute for GLD16,
//       XOR'd 16B-slot on ds_read) -> conflict-free. nt adj loads.
//   k4: out = 0.25 * sum_g (sum_kh C_kh)[i,512g+d] / (sum_kh S_kh)[g,i]
// ws ~85 MB: Wt 0.5M | HT 8M | Yt 8.65M | C 64M | S 0.5M

typedef unsigned short u16;
typedef unsigned int u32;
using bf16x8 = __attribute__((ext_vector_type(8))) short;
using f32x4  = __attribute__((ext_vector_type(4))) float;
using i32x4  = __attribute__((ext_vector_type(4))) int;

typedef const void __attribute__((address_space(1))) gas_void;
typedef void __attribute__((address_space(3))) las_void;
#define GLD16(g, l) __builtin_amdgcn_global_load_lds((gas_void*)(g), (las_void*)(l), 16, 0, 0)

__device__ __forceinline__ u16 f2bf(float f) {
  u32 u = __float_as_uint(f);
  return (u16)((u + 0x7FFFu + ((u >> 16) & 1u)) >> 16);  // RNE
}
__device__ __forceinline__ float bf2f(u16 u) {
  return __uint_as_float(((u32)u) << 16);
}

// ---------------- k0: transpose W [256][512] -> Wt [512][256] ----------------
__global__ void transpose_w(const float* __restrict__ W, float* __restrict__ Wt) {
  __shared__ float tile[32][33];
  int cb = blockIdx.x * 32, kb = blockIdx.y * 32;
  int tc = threadIdx.x & 31, tr = threadIdx.x >> 5;
  for (int p = 0; p < 32; p += 8)
    tile[tr + p][tc] = W[(size_t)(kb + tr + p) * 512 + cb + tc];
  __syncthreads();
  for (int p = 0; p < 32; p += 8)
    Wt[(size_t)(cb + tr + p) * 256 + kb + tc] = tile[tc][tr + p];
}

// ---------------- k1: HT = leaky(h @ W), bf16 out [8192][512] ----------------
__global__ void ht_gemm(const float* __restrict__ h, const float* __restrict__ Wt,
                        u16* __restrict__ HT) {
  __shared__ __align__(16) u16 Abuf[128 * 40];
  __shared__ __align__(16) u16 Bbuf[128 * 40];
  int tid = threadIdx.x;
  int cb = blockIdx.x, rb = blockIdx.y;
  int r0 = rb * 128, c0 = cb * 128;
  int lane = tid & 63, wv = tid >> 6;
  int wr = wv >> 1, wc = wv & 1;
  int mrow = lane & 15, q = lane >> 4;
  int ch = tid & 7, m0 = tid >> 3;

  f32x4 acc[4][4];
#pragma unroll
  for (int i = 0; i < 4; i++)
#pragma unroll
    for (int j = 0; j < 4; j++) acc[i][j] = f32x4{0.f, 0.f, 0.f, 0.f};

  for (int kt = 0; kt < 256; kt += 32) {
    __syncthreads();
#pragma unroll
    for (int mp = 0; mp < 128; mp += 32) {
      int m = m0 + mp;
      float4 v = *(const float4*)(&h[(size_t)(r0 + m) * 256 + kt + ch * 4]);
      uint2 p;
      p.x = (u32)f2bf(v.x) | ((u32)f2bf(v.y) << 16);
      p.y = (u32)f2bf(v.z) | ((u32)f2bf(v.w) << 16);
      *(uint2*)(&Abuf[m * 40 + ch * 4]) = p;
      float4 u = *(const float4*)(&Wt[(size_t)(c0 + m) * 256 + kt + ch * 4]);
      uint2 r;
      r.x = (u32)f2bf(u.x) | ((u32)f2bf(u.y) << 16);
      r.y = (u32)f2bf(u.z) | ((u32)f2bf(u.w) << 16);
      *(uint2*)(&Bbuf[m * 40 + ch * 4]) = r;
    }
    __syncthreads();
    bf16x8 af[4], bfv[4];
#pragma unroll
    for (int i = 0; i < 4; i++)
      af[i] = *(const bf16x8*)(&Abuf[(wr * 64 + i * 16 + mrow) * 40 + q * 8]);
#pragma unroll
    for (int j = 0; j < 4; j++)
      bfv[j] = *(const bf16x8*)(&Bbuf[(wc * 64 + j * 16 + mrow) * 40 + q * 8]);
#pragma unroll
    for (int i = 0; i < 4; i++)
#pragma unroll
      for (int j = 0; j < 4; j++)
        acc[i][j] = __builtin_amdgcn_mfma_f32_16x16x32_bf16(af[i], bfv[j], acc[i][j], 0, 0, 0);
  }
#pragma unroll
  for (int i = 0; i < 4; i++)
#pragma unroll
    for (int j = 0; j < 4; j++)
#pragma unroll
      for (int r = 0; r < 4; r++) {
        int gi = r0 + wr * 64 + i * 16 + q * 4 + r;
        int gc = c0 + wc * 64 + j * 16 + mrow;
        float v = acc[i][j][r];
        v = v >= 0.f ? v : 0.1f * v;
        HT[(size_t)gi * 512 + gc] = f2bf(v);
      }
}

// ---------------- k2: build Yt [528][8192] bf16 (32-j slabs, grid 256) -------
__global__ void build_yt(const u16* __restrict__ HT, const float* __restrict__ a,
                         u16* __restrict__ Yt) {
  __shared__ u16 sht[32][528];
  __shared__ float swv[32 * 4];
  __shared__ float sa[512];
  int t = threadIdx.x;
  int j0 = blockIdx.x * 32;
  for (int i = t; i < 512; i += 256) {
    int g = i >> 7, d = i & 127;
    sa[i] = a[g * 256 + 128 + d];
  }
#pragma unroll
  for (int p = 0; p < 8; ++p) {
    int el = t + 256 * p;                 // 2048 uint4 slots: 32 rows x 64
    int row = el >> 6, col8 = el & 63;
    *(uint4*)(&sht[row][col8 * 8]) = *(const uint4*)(&HT[(size_t)(j0 + row) * 512 + col8 * 8]);
  }
  __syncthreads();
  if (t < 128) {
    int jl = t >> 2, g = t & 3;
    float acc = 0.f;
#pragma unroll
    for (int d8 = 0; d8 < 16; ++d8) {
      bf16x8 v = *(const bf16x8*)(&sht[jl][g * 128 + d8 * 8]);
#pragma unroll
      for (int u = 0; u < 8; ++u)
        acc += bf2f((u16)v[u]) * sa[g * 128 + d8 * 8 + u];
    }
    swv[jl * 4 + g] = __expf(acc);
  }
  __syncthreads();
  int oj = (t & 3) * 8, oc = t >> 2;      // 4 j-octets x 64 cols per pass
  for (int pass = 0; pass < 9; ++pass) {
    int c = pass * 64 + oc;
    if (c >= 528) break;
    u32 pk[4] = {0u, 0u, 0u, 0u};
    if (c < 512) {
      int g = c >> 7;
#pragma unroll
      for (int u = 0; u < 4; ++u) {
        int j = oj + 2 * u;
        float v0 = bf2f(sht[j][c]) * swv[j * 4 + g];
        float v1 = bf2f(sht[j + 1][c]) * swv[(j + 1) * 4 + g];
        pk[u] = (u32)f2bf(v0) | ((u32)f2bf(v1) << 16);
      }
    } else if (c < 516) {
      int g = c - 512;
#pragma unroll
      for (int u = 0; u < 4; ++u) {
        int j = oj + 2 * u;
        float v0 = swv[j * 4 + g];
        float v1 = swv[(j + 1) * 4 + g];
        pk[u] = (u32)f2bf(v0) | ((u32)f2bf(v1) << 16);
      }
    }
    *(uint4*)(&Yt[(size_t)c * 8192 + j0 + oj]) = make_uint4(pk[0], pk[1], pk[2], pk[3]);
  }
}

// ---------------- k3: adj GEMM v7 -- 2-ahead GLD16, counted vmcnt ----------
// grid (4, 64) = (kh, rb): XCD = linear%8 in {kh, kh+4} -> each XCD's L2
// holds ONE 2.16 MB Yt quarter. 512 threads = 8 waves (2wr x 4wc).
// Per step t: A(t+1) nt-loads (oldest), GLD16 tile t+2 -> 3rd buffer,
// MFMA tile t, pack A(t+1), s_waitcnt vmcnt(4|5) -- retires tile t+1's
// GLD16s only, tile t+2's loads SURVIVE the barrier (T4).
// XOR swizzle (r1-proven, 0 conflicts): GLD16 global source octet
// bq = (lane&3)^((lane>>3)&3); ds_read slot qs = q^((mrow>>1)&3).
__global__ __launch_bounds__(512) void adj_gemm(const int* __restrict__ adj,
                                                const u16* __restrict__ Yt,
                                                float* __restrict__ C,
                                                float* __restrict__ S) {
  __shared__ __align__(16) u16 Bbuf[3][512 * 32];   // 96 KB
  __shared__ __align__(16) u16 Bden[3][16 * 32];    // 3 KB
  __shared__ __align__(16) u16 Abuf[2][128 * 32];   // 16 KB
  int tid = threadIdx.x;
  int rb = blockIdx.y, kh = blockIdx.x;             // kh fastest -> XCD pin
  int r0 = rb * 128, k0 = kh * 2048;
  int lane = tid & 63, wv = tid >> 6;
  int wr = wv >> 2, wc = wv & 3;
  int mrow = lane & 15, q = lane >> 4;
  int qs = q ^ ((mrow >> 1) & 3);                   // swizzled read slot
  int am = tid >> 2, aq = tid & 3;                  // A staging row / slot
  int asw = am * 32 + ((aq ^ ((am >> 1) & 3)) * 8); // swizzled A store off
  const int* abase = &adj[(size_t)(r0 + am) * 8192 + k0 + aq * 8];
  int brow = lane >> 2;
  int bq = (lane & 3) ^ ((lane >> 3) & 3);          // pre-swizzled src octet
  bool do_den = (wc == 0);

  f32x4 acc[4][8];
#pragma unroll
  for (int i = 0; i < 4; i++)
#pragma unroll
    for (int j = 0; j < 8; j++) acc[i][j] = f32x4{0.f, 0.f, 0.f, 0.f};
  f32x4 accD[4];
#pragma unroll
  for (int i = 0; i < 4; i++) accD[i] = f32x4{0.f, 0.f, 0.f, 0.f};

#define LOADA(V0, V1, TT)                                              \
  {                                                                    \
    const int* ap = abase + (size_t)(TT) * 32;                         \
    V0 = __builtin_nontemporal_load((const i32x4*)(ap));               \
    V1 = __builtin_nontemporal_load((const i32x4*)(ap + 4));           \
  }
#define PACKA(DST, V0, V1)                                             \
  {                                                                    \
    uint4 pk;                                                          \
    pk.x = 16256u * ((u32)V0[0] | ((u32)V0[1] << 16));                 \
    pk.y = 16256u * ((u32)V0[2] | ((u32)V0[3] << 16));                 \
    pk.z = 16256u * ((u32)V1[0] | ((u32)V1[1] << 16));                 \
    pk.w = 16256u * ((u32)V1[2] | ((u32)V1[3] << 16));                 \
    *(uint4*)((DST) + asw) = pk;                                       \
  }
#define STAGE_B(DB, DD, KT)                                            \
  {                                                                    \
    _Pragma("unroll") for (int p = 0; p < 4; ++p)                      \
        GLD16(&Yt[(size_t)(p * 128 + wv * 16 + brow) * 8192 + (KT) + bq * 8], \
              (DB) + (p * 128 + wv * 16) * 32);                        \
    if (wv == 0)                                                       \
      GLD16(&Yt[(size_t)(512 + brow) * 8192 + (KT) + bq * 8], (DD));   \
  }
#define WAIT_KEEP_ONE()                                                \
  {                                                                    \
    if (wv == 0) asm volatile("s_waitcnt vmcnt(5)" ::: "memory");      \
    else         asm volatile("s_waitcnt vmcnt(4)" ::: "memory");      \
  }

  // ---- prologue: A(0) -> Abuf[0]; GLD16 tiles 0,1 -> Bbuf[0],Bbuf[1] ----
  {
    i32x4 a0, a1;
    LOADA(a0, a1, 0);
    __builtin_amdgcn_sched_barrier(0);
    STAGE_B(&Bbuf[0][0], &Bden[0][0], k0);
    STAGE_B(&Bbuf[1][0], &Bden[1][0], k0 + 32);
    PACKA(&Abuf[0][0], a0, a1);     // waits A-loads (oldest); GLD16s remain
    WAIT_KEEP_ONE();                // retire tile0; tile1 stays in flight
    asm volatile("s_waitcnt lgkmcnt(0)" ::: "memory");
    __builtin_amdgcn_s_barrier();
  }

  u16 *bcur = &Bbuf[0][0], *bnxt = &Bbuf[1][0], *bnn = &Bbuf[2][0];
  u16 *dcur = &Bden[0][0], *dnxt = &Bden[1][0], *dnn = &Bden[2][0];

  for (int t = 0; t < 64; ++t) {
    i32x4 v0, v1;
    if (t < 63) {
      LOADA(v0, v1, t + 1);                       // oldest vmem this step
      __builtin_amdgcn_sched_barrier(0);          // keep before GLD16s
    }
    if (t < 62) STAGE_B(bnn, dnn, k0 + (t + 2) * 32);
    // ---- compute tile t ----
    bf16x8 af[4], bfv[8];
    const u16* Ab = &Abuf[t & 1][0];
#pragma unroll
    for (int i = 0; i < 4; i++)
      af[i] = *(const bf16x8*)(&Ab[(wr * 64 + i * 16 + mrow) * 32 + qs * 8]);
#pragma unroll
    for (int j = 0; j < 8; j++)
      bfv[j] = *(const bf16x8*)(&bcur[(wc * 128 + j * 16 + mrow) * 32 + qs * 8]);
    __builtin_amdgcn_s_setprio(1);
#pragma unroll
    for (int i = 0; i < 4; i++)
#pragma unroll
      for (int j = 0; j < 8; j++)
        acc[i][j] = __builtin_amdgcn_mfma_f32_16x16x32_bf16(af[i], bfv[j], acc[i][j], 0, 0, 0);
    if (do_den) {
      bf16x8 bd = *(const bf16x8*)(&dcur[mrow * 32 + qs * 8]);
#pragma unroll
      for (int i = 0; i < 4; i++)
        accD[i] = __builtin_amdgcn_mfma_f32_16x16x32_bf16(af[i], bd, accD[i], 0, 0, 0);
    }
    __builtin_amdgcn_s_setprio(0);
    // ---- finish staging A(t+1) ----
    if (t < 63) PACKA(&Abuf[(t + 1) & 1][0], v0, v1);
    // ---- retire tile t+1's GLD16s; tile t+2's stay in flight ----
    if (t < 62) {
      WAIT_KEEP_ONE();
    } else if (t == 62) {
      asm volatile("s_waitcnt vmcnt(0)" ::: "memory");
    }
    if (t < 63) {
      asm volatile("s_waitcnt lgkmcnt(0)" ::: "memory");
      __builtin_amdgcn_s_barrier();
    }
    u16* tb = bcur; bcur = bnxt; bnxt = bnn; bnn = tb;
    u16* td = dcur; dcur = dnxt; dnxt = dnn; dnn = td;
  }
#undef LOADA
#undef PACKA
#undef STAGE_B
#undef WAIT_KEEP_ONE

  float* Ck = C + (size_t)kh * 8192 * 512;
#pragma unroll
  for (int i = 0; i < 4; i++)
#pragma unroll
    for (int j = 0; j < 8; j++)
#pragma unroll
      for (int r = 0; r < 4; r++) {
        int gi = r0 + wr * 64 + i * 16 + q * 4 + r;
        int gc = wc * 128 + j * 16 + mrow;
        Ck[(size_t)gi * 512 + gc] = acc[i][j][r];
      }
  if (do_den && mrow < 4) {
    float* Sk = S + (size_t)kh * 4 * 8192;
#pragma unroll
    for (int i = 0; i < 4; i++)
#pragma unroll
      for (int r = 0; r < 4; r++) {
        int gi = r0 + wr * 64 + i * 16 + q * 4 + r;
        Sk[(size_t)mrow * 8192 + gi] = accD[i][r];
      }
  }
}

// ---------------- k4: combine K-split + heads ----------------
__global__ void finalize_gat(const float* __restrict__ C, const float* __restrict__ S,
                             float* __restrict__ out) {
  int idx = blockIdx.x * 256 + threadIdx.x;
  int i = idx >> 7, d = idx & 127;
  float s = 0.f;
#pragma unroll
  for (int g = 0; g < 4; ++g) {
    float num = 0.f, den = 0.f;
#pragma unroll
    for (int kh = 0; kh < 4; ++kh) {
      num += C[(size_t)kh * 8192 * 512 + (size_t)i * 512 + g * 128 + d];
      den += S[(size_t)kh * 4 * 8192 + (size_t)g * 8192 + i];
    }
    s += num / den;
  }
  out[idx] = 0.25f * s;
}

extern "C" void kernel_launch(void* const* d_in, const int* in_sizes, int n_in,
                              void* d_out, int out_size, void* d_ws, size_t ws_size,
                              hipStream_t stream) {
  const float* h   = (const float*)d_in[0];
  const int*   adj = (const int*)d_in[1];
  const float* W   = (const float*)d_in[2];
  const float* a   = (const float*)d_in[3];
  float* out = (float*)d_out;
  char* ws = (char*)d_ws;
  // ws: Wt 0.5M | HT 8M | Yt 8.65M | C 64M (4 x 16M) | S 0.5M  (~85 MB)
  float* Wt = (float*)(ws + 0);
  u16*   HT = (u16*)(ws + 524288);
  u16*   Yt = (u16*)(ws + 8912896);
  float* C  = (float*)(ws + 17563648);
  float* S  = (float*)(ws + 84672512);

  transpose_w<<<dim3(16, 8), 256, 0, stream>>>(W, Wt);
  ht_gemm<<<dim3(4, 64), 256, 0, stream>>>(h, Wt, HT);
  build_yt<<<dim3(256), 256, 0, stream>>>(HT, a, Yt);
  adj_gemm<<<dim3(4, 64), 512, 0, stream>>>(adj, Yt, C, S);
  finalize_gat<<<dim3(4096), 256, 0, stream>>>(C, S, out);
}